// Round 1
// baseline (559.751 us; speedup 1.0000x reference)
//
#include <hip/hip_runtime.h>
#include <hip/hip_bf16.h>

// Graph message-passing layer, bf16 MFMA implementation.
// N=10000 nodes, E=640000 edges, F=M=O=128.

#define NN 10000
#define NE 640000

typedef __attribute__((ext_vector_type(8))) short short8;
typedef __attribute__((ext_vector_type(4))) float floatx4;

__device__ __forceinline__ short f2bf(float f) {
    union { float f; unsigned u; } v; v.f = f;
    unsigned r = v.u + 0x7fffu + ((v.u >> 16) & 1u);   // RNE, NaN-free inputs
    return (short)(r >> 16);
}

__device__ __forceinline__ float sigmoidf_(float x) {
    return __builtin_amdgcn_rcpf(1.f + __expf(-x));
}
__device__ __forceinline__ float softsignf_(float x) {
    return x * __builtin_amdgcn_rcpf(1.f + fabsf(x));
}

// dst[c][k] = bf16(src[k][c])  (col-major bf16 weights so B-fragments are
// contiguous 16B loads)
__global__ void prep_transpose(const float* __restrict__ src,
                               short* __restrict__ dst, int K, int C) {
    int i = blockIdx.x * 256 + threadIdx.x;
    if (i >= K * C) return;
    int c = i / K, k = i - c * K;
    dst[i] = f2bf(src[k * C + c]);
}

// Edge kernel: 4 waves/block, 16 edges/wave.
// GEMM1: [16,256]x[256,128]; GEMM2: [16,128]x[128,128]; scatter via atomics.
__global__ __launch_bounds__(256) void edge_kernel(
    const float* __restrict__ feat,
    const int* __restrict__ rows,
    const int* __restrict__ cols,
    const short* __restrict__ Wm1T,
    const float* __restrict__ bm1,
    const short* __restrict__ Wm2T,
    const float* __restrict__ bm2,
    float* __restrict__ agg)
{
    __shared__ __align__(16) short hbuf[4][16][128];
    const int tid = threadIdx.x;
    const int w = tid >> 6, l = tid & 63;
    const int l15 = l & 15, q = l >> 4;
    const int ebase = blockIdx.x * 64 + w * 16;

    // A-operand gather: lane serves edge (l&15), k-slice q*8..q*8+7 per k-tile
    const int eA = ebase + l15;
    const int rs = rows[eA];
    const int rd = cols[eA];
    const float* srcp = feat + (size_t)rs * 128 + q * 8;
    const float* dstp = feat + (size_t)rd * 128 + q * 8;

    floatx4 acc[8];
#pragma unroll
    for (int i = 0; i < 8; ++i) acc[i] = (floatx4)(0.f);

#pragma unroll
    for (int kk = 0; kk < 8; ++kk) {                    // K = 256 = 8 x 32
        const float* ap = (kk < 4) ? (srcp + kk * 32) : (dstp + (kk - 4) * 32);
        const float4 a0 = *(const float4*)(ap);
        const float4 a1 = *(const float4*)(ap + 4);
        short8 af;
        af[0] = f2bf(a0.x); af[1] = f2bf(a0.y); af[2] = f2bf(a0.z); af[3] = f2bf(a0.w);
        af[4] = f2bf(a1.x); af[5] = f2bf(a1.y); af[6] = f2bf(a1.z); af[7] = f2bf(a1.w);
        const int krow = kk * 32 + q * 8;
#pragma unroll
        for (int ct = 0; ct < 8; ++ct) {
            const int col = ct * 16 + l15;
            short8 bf = *(const short8*)(Wm1T + col * 256 + krow);
            acc[ct] = __builtin_amdgcn_mfma_f32_16x16x32_bf16(af, bf, acc[ct], 0, 0, 0);
        }
    }

    // h = sigmoid(acc + bm1), write to LDS (C-layout -> A-layout transpose).
    // Each wave touches only hbuf[w]; same-wave dep, no barrier needed.
#pragma unroll
    for (int ct = 0; ct < 8; ++ct) {
        const int col = ct * 16 + l15;
        const float b = bm1[col];
#pragma unroll
        for (int r = 0; r < 4; ++r) {
            hbuf[w][q * 4 + r][col] = f2bf(sigmoidf_(acc[ct][r] + b));
        }
    }

    floatx4 acc2[8];
#pragma unroll
    for (int i = 0; i < 8; ++i) acc2[i] = (floatx4)(0.f);
#pragma unroll
    for (int kk = 0; kk < 4; ++kk) {                    // K = 128 = 4 x 32
        const int krow = kk * 32 + q * 8;
        short8 af = *(const short8*)(&hbuf[w][l15][krow]);
#pragma unroll
        for (int ct = 0; ct < 8; ++ct) {
            const int col = ct * 16 + l15;
            short8 bf = *(const short8*)(Wm2T + col * 128 + krow);
            acc2[ct] = __builtin_amdgcn_mfma_f32_16x16x32_bf16(af, bf, acc2[ct], 0, 0, 0);
        }
    }

    // messages = softsign(acc2 + bm2); scatter-add into agg[rows[e]]
    int nodebuf[4];
#pragma unroll
    for (int r = 0; r < 4; ++r) nodebuf[r] = rows[ebase + q * 4 + r];
#pragma unroll
    for (int ct = 0; ct < 8; ++ct) {
        const int col = ct * 16 + l15;
        const float b = bm2[col];
#pragma unroll
        for (int r = 0; r < 4; ++r) {
            const float m = softsignf_(acc2[ct][r] + b);
            atomicAdd(&agg[(size_t)nodebuf[r] * 128 + col], m);
        }
    }
}

// Node kernel: feat_in = sigmoid([features, agg, time_emb]) -> MLP -> out
__global__ __launch_bounds__(256) void node_kernel(
    const float* __restrict__ feat,
    const float* __restrict__ agg,
    const float* __restrict__ temb,
    const short* __restrict__ Wf1T,
    const float* __restrict__ bf1v,
    const short* __restrict__ Wf2T,
    const float* __restrict__ bf2v,
    float* __restrict__ out)
{
    __shared__ __align__(16) short gbuf[4][16][128];
    const int tid = threadIdx.x;
    const int w = tid >> 6, l = tid & 63;
    const int l15 = l & 15, q = l >> 4;
    const int nbase = blockIdx.x * 64 + w * 16;
    if (nbase >= NN) return;    // 10000 = 625 full waves; guard whole waves

    const int nA = nbase + l15;
    const float* p0 = feat + (size_t)nA * 128 + q * 8;
    const float* p1 = agg + (size_t)nA * 128 + q * 8;
    const float* p2 = temb + (size_t)nA * 128 + q * 8;

    floatx4 acc[8];
#pragma unroll
    for (int i = 0; i < 8; ++i) acc[i] = (floatx4)(0.f);

#pragma unroll
    for (int kk = 0; kk < 12; ++kk) {                   // K = 384 = 12 x 32
        const float* ap = (kk < 4) ? (p0 + kk * 32)
                        : (kk < 8) ? (p1 + (kk - 4) * 32)
                                   : (p2 + (kk - 8) * 32);
        const float4 a0 = *(const float4*)(ap);
        const float4 a1 = *(const float4*)(ap + 4);
        short8 af;
        af[0] = f2bf(sigmoidf_(a0.x)); af[1] = f2bf(sigmoidf_(a0.y));
        af[2] = f2bf(sigmoidf_(a0.z)); af[3] = f2bf(sigmoidf_(a0.w));
        af[4] = f2bf(sigmoidf_(a1.x)); af[5] = f2bf(sigmoidf_(a1.y));
        af[6] = f2bf(sigmoidf_(a1.z)); af[7] = f2bf(sigmoidf_(a1.w));
        const int krow = kk * 32 + q * 8;
#pragma unroll
        for (int ct = 0; ct < 8; ++ct) {
            const int col = ct * 16 + l15;
            short8 bf = *(const short8*)(Wf1T + col * 384 + krow);
            acc[ct] = __builtin_amdgcn_mfma_f32_16x16x32_bf16(af, bf, acc[ct], 0, 0, 0);
        }
    }

#pragma unroll
    for (int ct = 0; ct < 8; ++ct) {
        const int col = ct * 16 + l15;
        const float b = bf1v[col];
#pragma unroll
        for (int r = 0; r < 4; ++r) {
            gbuf[w][q * 4 + r][col] = f2bf(sigmoidf_(acc[ct][r] + b));
        }
    }

    floatx4 acc2[8];
#pragma unroll
    for (int i = 0; i < 8; ++i) acc2[i] = (floatx4)(0.f);
#pragma unroll
    for (int kk = 0; kk < 4; ++kk) {
        const int krow = kk * 32 + q * 8;
        short8 af = *(const short8*)(&gbuf[w][l15][krow]);
#pragma unroll
        for (int ct = 0; ct < 8; ++ct) {
            const int col = ct * 16 + l15;
            short8 bf = *(const short8*)(Wf2T + col * 128 + krow);
            acc2[ct] = __builtin_amdgcn_mfma_f32_16x16x32_bf16(af, bf, acc2[ct], 0, 0, 0);
        }
    }

#pragma unroll
    for (int ct = 0; ct < 8; ++ct) {
        const int col = ct * 16 + l15;
        const float b = bf2v[col];
#pragma unroll
        for (int r = 0; r < 4; ++r) {
            const int node = nbase + q * 4 + r;
            out[(size_t)node * 128 + col] = softsignf_(acc2[ct][r] + b);
        }
    }
}

extern "C" void kernel_launch(void* const* d_in, const int* in_sizes, int n_in,
                              void* d_out, int out_size, void* d_ws, size_t ws_size,
                              hipStream_t stream)
{
    const float* feat = (const float*)d_in[0];
    const int* rows = (const int*)d_in[1];
    const int* cols = (const int*)d_in[2];
    const float* temb = (const float*)d_in[3];
    const float* Wm1 = (const float*)d_in[4];
    const float* bm1 = (const float*)d_in[5];
    const float* Wm2 = (const float*)d_in[6];
    const float* bm2 = (const float*)d_in[7];
    const float* Wf1 = (const float*)d_in[8];
    const float* bf1 = (const float*)d_in[9];
    const float* Wf2 = (const float*)d_in[10];
    const float* bf2 = (const float*)d_in[11];
    float* out = (float*)d_out;

    // Workspace layout (all 16B-aligned):
    //   agg  f32 [10000][128]           5,120,000 B
    //   Wm1T bf16 [128][256]               65,536 B
    //   Wm2T bf16 [128][128]               32,768 B
    //   Wf1T bf16 [128][384]               98,304 B
    //   Wf2T bf16 [128][128]               32,768 B
    char* ws = (char*)d_ws;
    float* agg = (float*)ws;
    short* Wm1T = (short*)(ws + 5120000);
    short* Wm2T = (short*)(ws + 5120000 + 65536);
    short* Wf1T = (short*)(ws + 5120000 + 65536 + 32768);
    short* Wf2T = (short*)(ws + 5120000 + 65536 + 32768 + 98304);

    hipMemsetAsync(agg, 0, (size_t)NN * 128 * sizeof(float), stream);
    prep_transpose<<<(256 * 128 + 255) / 256, 256, 0, stream>>>(Wm1, Wm1T, 256, 128);
    prep_transpose<<<(128 * 128 + 255) / 256, 256, 0, stream>>>(Wm2, Wm2T, 128, 128);
    prep_transpose<<<(384 * 128 + 255) / 256, 256, 0, stream>>>(Wf1, Wf1T, 384, 128);
    prep_transpose<<<(128 * 128 + 255) / 256, 256, 0, stream>>>(Wf2, Wf2T, 128, 128);

    edge_kernel<<<NE / 64, 256, 0, stream>>>(feat, rows, cols, Wm1T, bm1, Wm2T, bm2, agg);
    node_kernel<<<(NN + 63) / 64, 256, 0, stream>>>(feat, agg, temb, Wf1T, bf1, Wf2T, bf2, out);
}